// Round 12
// baseline (116.113 us; speedup 1.0000x reference)
//
#include <hip/hip_runtime.h>

#define BN_EPS 1e-5f

typedef float f32x4 __attribute__((ext_vector_type(4)));
typedef short short8 __attribute__((ext_vector_type(8)));
typedef unsigned short u16;

__device__ __forceinline__ u16 f2bf(float f) {
    unsigned u = __builtin_bit_cast(unsigned, f);
    unsigned r = (u + 0x7FFFu + ((u >> 16) & 1u)) >> 16;   // round-nearest-even
    return (u16)r;
}
__device__ __forceinline__ float b2f(u16 h) {
    return __builtin_bit_cast(float, (unsigned)h << 16);
}

// two-term XOR swizzle (bits 4-6 of the byte offset)
#define SWZ(row) ((((row) & 7) ^ (((row) >> 3) & 7)) << 4)

// ---------------------------------------------------------------------------
// dw1 + prep fused: blocks [0,4096) depthwise 3x3 (HW=64, fp32->bf16);
// blocks [4096,4256) convert pw/cat weights to bf16.
// ---------------------------------------------------------------------------
__global__ __launch_bounds__(256) void dw1_prep(
    const float* __restrict__ in, const float* __restrict__ wts,
    u16* __restrict__ out,
    const float* __restrict__ w1, const float* __restrict__ w2,
    const float* __restrict__ wc, u16* __restrict__ o1,
    u16* __restrict__ o2, u16* __restrict__ oc)
{
    const int t = threadIdx.x;
    if (blockIdx.x >= 4096) {
        const int idx = (blockIdx.x - 4096) * 256 + t;     // [0, 40960)
        const float* src; u16* dst; int off;
        if (idx < 8192)       { src = w1; dst = o1; off = idx; }
        else if (idx < 24576) { src = w2; dst = o2; off = idx - 8192; }
        else                  { src = wc; dst = oc; off = idx - 24576; }
        const float4 v = *(const float4*)(src + 4 * (size_t)off);
        ushort4 h;
        h.x = f2bf(v.x); h.y = f2bf(v.y); h.z = f2bf(v.z); h.w = f2bf(v.w);
        *(ushort4*)(dst + 4 * (size_t)off) = h;
        return;
    }

    const int HW = 64;
    const int wq  = t & 15;
    const int w0  = wq * 4;
    const int rin = t >> 4;
    const int plane = blockIdx.x;
    const int c     = plane & 127;
    float wt[9];
#pragma unroll
    for (int i = 0; i < 9; ++i) wt[i] = wts[c * 9 + i];
    const float* ip = in  + (size_t)plane * (HW * HW);
    u16*         op = out + (size_t)plane * (HW * HW);

#pragma unroll
    for (int it = 0; it < 4; ++it) {
        const int h = it * 16 + rin;
        const float* rp = ip + h * HW + w0;
        const float4 zero4 = make_float4(0.f, 0.f, 0.f, 0.f);
        const float4 vc = *(const float4*)rp;
        const float4 vt = (h > 0)      ? *(const float4*)(rp - HW) : zero4;
        const float4 vb = (h < HW - 1) ? *(const float4*)(rp + HW) : zero4;

        float lc = __shfl_up(vc.w, 1),  rc = __shfl_down(vc.x, 1);
        float lt = __shfl_up(vt.w, 1),  rt = __shfl_down(vt.x, 1);
        float lb = __shfl_up(vb.w, 1),  rb = __shfl_down(vb.x, 1);
        if (wq == 0)  { lc = 0.f; lt = 0.f; lb = 0.f; }
        if (wq == 15) { rc = 0.f; rt = 0.f; rb = 0.f; }

        float o0 = 0.f, o1v = 0.f, o2v = 0.f, o3v = 0.f;
        o0  = fmaf(lt,   wt[0], fmaf(vt.x, wt[1], fmaf(vt.y, wt[2], o0)));
        o1v = fmaf(vt.x, wt[0], fmaf(vt.y, wt[1], fmaf(vt.z, wt[2], o1v)));
        o2v = fmaf(vt.y, wt[0], fmaf(vt.z, wt[1], fmaf(vt.w, wt[2], o2v)));
        o3v = fmaf(vt.z, wt[0], fmaf(vt.w, wt[1], fmaf(rt,   wt[2], o3v)));
        o0  = fmaf(lc,   wt[3], fmaf(vc.x, wt[4], fmaf(vc.y, wt[5], o0)));
        o1v = fmaf(vc.x, wt[3], fmaf(vc.y, wt[4], fmaf(vc.z, wt[5], o1v)));
        o2v = fmaf(vc.y, wt[3], fmaf(vc.z, wt[4], fmaf(vc.w, wt[5], o2v)));
        o3v = fmaf(vc.z, wt[3], fmaf(vc.w, wt[4], fmaf(rc,   wt[5], o3v)));
        o0  = fmaf(lb,   wt[6], fmaf(vb.x, wt[7], fmaf(vb.y, wt[8], o0)));
        o1v = fmaf(vb.x, wt[6], fmaf(vb.y, wt[7], fmaf(vb.z, wt[8], o1v)));
        o2v = fmaf(vb.y, wt[6], fmaf(vb.z, wt[7], fmaf(vb.w, wt[8], o2v)));
        o3v = fmaf(vb.z, wt[6], fmaf(vb.w, wt[7], fmaf(rb,   wt[8], o3v)));

        ushort4 st;
        st.x = f2bf(o0); st.y = f2bf(o1v); st.z = f2bf(o2v); st.w = f2bf(o3v);
        *(ushort4*)(op + h * HW + w0) = st;
    }
}

// ---------------------------------------------------------------------------
// pw1_v2: one block per (b, py) X-tile. 256o x 128px, K=128 resident.
// NEW epilogue: pooled output transposed in LDS -> t2bT [b][1024px][256c] bf16.
// ---------------------------------------------------------------------------
__global__ __launch_bounds__(256, 2) void pw1_v2(
    const u16* __restrict__ t1b, const u16* __restrict__ wsW1,
    const float* __restrict__ bg, const float* __restrict__ bb,
    const float* __restrict__ bm, const float* __restrict__ bv,
    u16* __restrict__ t2bT)
{
    __shared__ __align__(16) char smem[34816];       // B 32K (reused as T) | sArr | tArr
    float* sArr = (float*)(smem + 32768);
    float* tArr = (float*)(smem + 33792);

    const int bid = blockIdx.x;
    const int b   = bid >> 5;
    const int py  = bid & 31;
    const int p0  = py * 128;
    const int t   = threadIdx.x;

    {
        const float s = bg[t] * rsqrtf(bv[t] + BN_EPS);
        sArr[t] = s;
        tArr[t] = bb[t] - bm[t] * s;
    }

    // stage B: 8x8 register transpose of t1b tile -> [p][c] swz
    {
        const u16* xb = t1b + ((size_t)b * 128) * 4096 + p0;
        const int pg = t & 15, cg = t >> 4;
        short8 vin[8];
#pragma unroll
        for (int j = 0; j < 8; ++j)
            vin[j] = *(const short8*)(xb + (size_t)(8 * cg + j) * 4096 + 8 * pg);
#pragma unroll
        for (int k = 0; k < 8; ++k) {
            short8 ov;
            ov[0] = vin[0][k]; ov[1] = vin[1][k]; ov[2] = vin[2][k]; ov[3] = vin[3][k];
            ov[4] = vin[4][k]; ov[5] = vin[5][k]; ov[6] = vin[6][k]; ov[7] = vin[7][k];
            const int row = 8 * pg + k;
            *(short8*)(smem + ((row * 256 + cg * 16) ^ SWZ(row))) = ov;
        }
    }
    __syncthreads();

    const int lane = t & 63, wid = t >> 6;
    const int lr = lane & 15, lg = lane >> 4;
    const int wo = wid * 64;

    f32x4 acc[4][8];
#pragma unroll
    for (int m = 0; m < 4; ++m)
#pragma unroll
        for (int n = 0; n < 8; ++n) acc[m][n] = (f32x4){0.f, 0.f, 0.f, 0.f};

    const u16* wbase = wsW1 + (size_t)(wo + lr) * 128 + lg * 8;
#pragma unroll
    for (int ks = 0; ks < 4; ++ks) {
        short8 af[4];
#pragma unroll
        for (int m = 0; m < 4; ++m)
            af[m] = *(const short8*)(wbase + m * 16 * 128 + ks * 32);
#pragma unroll
        for (int n = 0; n < 8; ++n) {
            const int prow = n * 16 + lr;
            const short8 bfv = *(const short8*)(smem +
                ((prow * 256 + ks * 64 + lg * 16) ^ SWZ(prow)));
#pragma unroll
            for (int m = 0; m < 4; ++m)
                acc[m][n] = __builtin_amdgcn_mfma_f32_16x16x32_bf16(af[m], bfv, acc[m][n], 0, 0, 0);
        }
    }
    __syncthreads();   // MFMA B-reads done; reuse smem as T [32pc][264 u16]

    // pool (vertical n/n+4, horizontal shfl) -> T[pc][o] u16
#pragma unroll
    for (int m = 0; m < 4; ++m) {
#pragma unroll
        for (int n = 0; n < 4; ++n) {
            ushort4 h;
#pragma unroll
            for (int j = 0; j < 4; ++j) {
                const int o = wo + m * 16 + 4 * lg + j;
                const float s = sArr[o], tt = tArr[o];
                const float a0 = fmaxf(fmaf(acc[m][n][j],     s, tt), 0.f);
                const float a1 = fmaxf(fmaf(acc[m][n + 4][j], s, tt), 0.f);
                const float vm = fmaxf(a0, a1);
                const float hm = fmaxf(vm, __shfl_xor(vm, 1));
                ((u16*)&h)[j] = f2bf(hm);
            }
            if ((lr & 1) == 0) {
                const int pc = n * 8 + (lr >> 1);
                *(ushort4*)(smem + pc * 528 + (wo + m * 16 + 4 * lg) * 2) = h;
            }
        }
    }
    __syncthreads();

    // coalesced store: t2bT[b][py*32+pc][c], 512B rows
    {
        const int px = t >> 3;
        const int c0 = (t & 7) * 32;
        const char* Trow = smem + px * 528 + c0 * 2;
        u16* dst = t2bT + ((size_t)(b * 1024 + py * 32 + px)) * 256 + c0;
#pragma unroll
        for (int i = 0; i < 4; ++i)
            *(short8*)(dst + i * 8) = *(const short8*)(Trow + i * 16);
    }
}

// ---------------------------------------------------------------------------
// pw2_v3: fused dw2(3x3 on 32x32, px-major) + pw1x1 MFMA + BN+ReLU+pool.
// 512 blocks = (b, T row-pair). Block: 256o x 64px (image rows 2T,2T+1),
// K=256 as 2 stages; B staged by conv-on-the-fly from t2bT; A direct from
// bf16 W2 global (L2). Output xout fp32 [32][256][16][16] (pooled row T).
// ---------------------------------------------------------------------------
__global__ __launch_bounds__(256) void pw2_v3(
    const u16* __restrict__ t2bT, const u16* __restrict__ wsW2,
    const float* __restrict__ w2dw,
    const float* __restrict__ bg, const float* __restrict__ bb,
    const float* __restrict__ bm, const float* __restrict__ bv,
    float* __restrict__ xout)
{
    __shared__ __align__(16) char smem[27648];
    // Bs [64px][256B] @0 (16K) | wJ [9][256] f32 @16384 (9K) | sArr @25600 | tArr @26624
    float* wJ   = (float*)(smem + 16384);
    float* sArr = (float*)(smem + 25600);
    float* tArr = (float*)(smem + 26624);

    const int bid = blockIdx.x;
    const int b   = bid >> 4;
    const int T   = bid & 15;
    const int t   = threadIdx.x;

    {
        const float s = bg[t] * rsqrtf(bv[t] + BN_EPS);
        sArr[t] = s;
        tArr[t] = bb[t] - bm[t] * s;
        // transpose dw weights: wJ[j][c]
#pragma unroll
        for (int j = 0; j < 9; ++j) wJ[j * 256 + t] = w2dw[t * 9 + j];
    }
    __syncthreads();

    const int lane = t & 63, wid = t >> 6;
    const int lr = lane & 15, lg = lane >> 4;
    const int wo = wid * 64;

    f32x4 acc[4][4];
#pragma unroll
    for (int m = 0; m < 4; ++m)
#pragma unroll
        for (int n = 0; n < 4; ++n) acc[m][n] = (f32x4){0.f, 0.f, 0.f, 0.f};

    const int co  = t & 3;          // 32-channel group within 128-c stage
    const int pxq = t >> 2;         // px in [0,64)
    const int rl  = pxq >> 5;       // local row 0/1
    const int cl  = pxq & 31;       // col

#pragma unroll
    for (int ko = 0; ko < 2; ++ko) {
        if (ko) __syncthreads();    // prior MFMA reads done before Bs overwrite

        // ---- conv-on-the-fly staging: Bs[px][128c] = dw2(t2bT) ----
        {
            float ac[32];
#pragma unroll
            for (int i = 0; i < 32; ++i) ac[i] = 0.f;
            const int cbase = ko * 128 + co * 32;
#pragma unroll
            for (int j = 0; j < 9; ++j) {
                const int dr = j / 3 - 1, dc = j % 3 - 1;
                const int gr = 2 * T + rl + dr;
                const int gc = cl + dc;
                const bool ok = (gr >= 0) && (gr < 32) && (gc >= 0) && (gc < 32);
                const u16* src = t2bT + ((size_t)(b * 1024 + gr * 32 + gc)) * 256 + cbase;
                const float* wj = wJ + j * 256 + cbase;
#pragma unroll
                for (int i4 = 0; i4 < 4; ++i4) {
                    short8 v;
                    if (ok) v = *(const short8*)(src + i4 * 8);
                    else    v = (short8){0,0,0,0,0,0,0,0};
                    const float4 wa = *(const float4*)(wj + i4 * 8);
                    const float4 wb = *(const float4*)(wj + i4 * 8 + 4);
                    ac[i4*8+0] = fmaf(b2f((u16)v[0]), wa.x, ac[i4*8+0]);
                    ac[i4*8+1] = fmaf(b2f((u16)v[1]), wa.y, ac[i4*8+1]);
                    ac[i4*8+2] = fmaf(b2f((u16)v[2]), wa.z, ac[i4*8+2]);
                    ac[i4*8+3] = fmaf(b2f((u16)v[3]), wa.w, ac[i4*8+3]);
                    ac[i4*8+4] = fmaf(b2f((u16)v[4]), wb.x, ac[i4*8+4]);
                    ac[i4*8+5] = fmaf(b2f((u16)v[5]), wb.y, ac[i4*8+5]);
                    ac[i4*8+6] = fmaf(b2f((u16)v[6]), wb.z, ac[i4*8+6]);
                    ac[i4*8+7] = fmaf(b2f((u16)v[7]), wb.w, ac[i4*8+7]);
                }
            }
#pragma unroll
            for (int ii = 0; ii < 8; ++ii) {
                ushort4 h;
                h.x = f2bf(ac[4*ii+0]); h.y = f2bf(ac[4*ii+1]);
                h.z = f2bf(ac[4*ii+2]); h.w = f2bf(ac[4*ii+3]);
                *(ushort4*)(smem + ((pxq * 256 + (co * 32 + 4 * ii) * 2) ^ SWZ(pxq))) = h;
            }
        }
        __syncthreads();

        // ---- MFMA: A direct from global bf16 W2, B from Bs ----
        const u16* wbase = wsW2 + (size_t)(wo + lr) * 256 + ko * 128 + lg * 8;
#pragma unroll
        for (int ks = 0; ks < 4; ++ks) {
            short8 af[4];
#pragma unroll
            for (int m = 0; m < 4; ++m)
                af[m] = *(const short8*)(wbase + m * 16 * 256 + ks * 32);
#pragma unroll
            for (int n = 0; n < 4; ++n) {
                const int prow = n * 16 + lr;
                const short8 bfv = *(const short8*)(smem +
                    ((prow * 256 + ks * 64 + lg * 16) ^ SWZ(prow)));
#pragma unroll
                for (int m = 0; m < 4; ++m)
                    acc[m][n] = __builtin_amdgcn_mfma_f32_16x16x32_bf16(af[m], bfv, acc[m][n], 0, 0, 0);
            }
        }
    }

    // ---- BN + ReLU + 2x2 pool -> xout[b][o][T][16] ----
#pragma unroll
    for (int m = 0; m < 4; ++m) {
#pragma unroll
        for (int j = 0; j < 4; ++j) {
            const int o = wo + m * 16 + 4 * lg + j;
            const float s = sArr[o], tt = tArr[o];
#pragma unroll
            for (int nv = 0; nv < 2; ++nv) {
                const float a0 = fmaxf(fmaf(acc[m][nv][j],     s, tt), 0.f);
                const float a1 = fmaxf(fmaf(acc[m][nv + 2][j], s, tt), 0.f);
                const float vm = fmaxf(a0, a1);
                const float hm = fmaxf(vm, __shfl_xor(vm, 1));     // even lr
                const float h1 = __shfl_xor(hm, 2);                // pc+1
                const float g0 = __shfl_xor(hm, 4);                // pc+2
                const float g1 = __shfl_xor(h1, 4);                // pc+3
                if ((lr & 7) == 0) {
                    float4 f4 = make_float4(hm, h1, g0, g1);
                    *(float4*)(xout + ((size_t)(b * 256 + o)) * 256 + T * 16 +
                               nv * 8 + (lr >> 1)) = f4;
                }
            }
        }
    }
}

// ---------------------------------------------------------------------------
// cat_v2: 1024 blocks = (b, m-block, px-quarter). Single-stage.
// ---------------------------------------------------------------------------
__global__ __launch_bounds__(256) void cat_v2(
    const float* __restrict__ x, const u16* __restrict__ wsWc,
    float* __restrict__ spikes, float* __restrict__ csws)
{
    __shared__ __align__(16) char smem[49664];   // A 16K @0 | B 32K @16384 | cs
    float* cs = (float*)(smem + 49152);          // [4][32]

    const int bid = blockIdx.x;
    const int g   = (bid >> 6) * 8 + (bid & 7);  // [0,128)
    const int m0  = ((bid >> 3) & 7) * 32;
    const int b   = g >> 2;
    const int q   = g & 3;
    const int px0 = q * 64;
    const int t   = threadIdx.x;

#pragma unroll
    for (int i = 0; i < 4; ++i) {
        const int li = i * 256 + t;
        const int ml = li >> 5, ch = li & 31;
        const short8 wv = *(const short8*)(wsWc + (size_t)(m0 + ml) * 256 + ch * 8);
        *(short8*)(smem + ((ml * 512 + ch * 16) ^ SWZ(ml))) = wv;
    }

    const float* xb = x + (size_t)b * 65536;
#pragma unroll
    for (int i = 0; i < 4; ++i) {
        const int li = i * 256 + t;
        const int pq = li & 15;
        const int cg = li >> 4;
        const float4 v0 = *(const float4*)(xb + (size_t)(4 * cg + 0) * 256 + px0 + 4 * pq);
        const float4 v1 = *(const float4*)(xb + (size_t)(4 * cg + 1) * 256 + px0 + 4 * pq);
        const float4 v2 = *(const float4*)(xb + (size_t)(4 * cg + 2) * 256 + px0 + 4 * pq);
        const float4 v3 = *(const float4*)(xb + (size_t)(4 * cg + 3) * 256 + px0 + 4 * pq);
        ushort4 h0, h1, h2, h3;
        h0.x = f2bf(v0.x); h0.y = f2bf(v1.x); h0.z = f2bf(v2.x); h0.w = f2bf(v3.x);
        h1.x = f2bf(v0.y); h1.y = f2bf(v1.y); h1.z = f2bf(v2.y); h1.w = f2bf(v3.y);
        h2.x = f2bf(v0.z); h2.y = f2bf(v1.z); h2.z = f2bf(v2.z); h2.w = f2bf(v3.z);
        h3.x = f2bf(v0.w); h3.y = f2bf(v1.w); h3.z = f2bf(v2.w); h3.w = f2bf(v3.w);
        const int p_ = 4 * pq;
        *(ushort4*)(smem + 16384 + (((p_ + 0) * 512 + cg * 8) ^ SWZ(p_ + 0))) = h0;
        *(ushort4*)(smem + 16384 + (((p_ + 1) * 512 + cg * 8) ^ SWZ(p_ + 1))) = h1;
        *(ushort4*)(smem + 16384 + (((p_ + 2) * 512 + cg * 8) ^ SWZ(p_ + 2))) = h2;
        *(ushort4*)(smem + 16384 + (((p_ + 3) * 512 + cg * 8) ^ SWZ(p_ + 3))) = h3;
    }
    __syncthreads();

    const int lane = t & 63, wid = t >> 6;
    const int lr = lane & 15, lg = lane >> 4;

    f32x4 acc[2];
    acc[0] = (f32x4){0.f, 0.f, 0.f, 0.f};
    acc[1] = (f32x4){0.f, 0.f, 0.f, 0.f};

#pragma unroll
    for (int ks = 0; ks < 8; ++ks) {
        const int prow = wid * 16 + lr;
        const short8 b8 = *(const short8*)(smem + 16384 +
            ((prow * 512 + ks * 64 + lg * 16) ^ SWZ(prow)));
#pragma unroll
        for (int mi = 0; mi < 2; ++mi) {
            const int rowm = mi * 16 + lr;
            const short8 a8 = *(const short8*)(smem +
                ((rowm * 512 + ks * 64 + lg * 16) ^ SWZ(rowm)));
            acc[mi] = __builtin_amdgcn_mfma_f32_16x16x32_bf16(a8, b8, acc[mi], 0, 0, 0);
        }
    }

#pragma unroll
    for (int mi = 0; mi < 2; ++mi) {
#pragma unroll
        for (int j = 0; j < 4; ++j) {
            const int m  = m0 + mi * 16 + 4 * lg + j;
            const int px = px0 + wid * 16 + lr;
            spikes[((size_t)(b * 256 + m)) * 256 + px] = acc[mi][j];
            float s = acc[mi][j];
            s += __shfl_xor(s, 1, 64);
            s += __shfl_xor(s, 2, 64);
            s += __shfl_xor(s, 4, 64);
            s += __shfl_xor(s, 8, 64);
            if (lr == 0) cs[wid * 32 + mi * 16 + 4 * lg + j] = s;
        }
    }
    __syncthreads();
    if (t < 32) {
        const float p = cs[t] + cs[32 + t] + cs[64 + t] + cs[96 + t];
        csws[((size_t)(b * 256 + m0 + t)) * 4 + q] = p;
    }
}

// ---------------------------------------------------------------------------
// final: pooled mean + embedding GEMV + cat_act from partials.
// ---------------------------------------------------------------------------
__global__ __launch_bounds__(256) void final_kernel(
    const float* __restrict__ x, const float* __restrict__ csws,
    const float* __restrict__ embw, const float* __restrict__ embb,
    float* __restrict__ cat_act, float* __restrict__ emb)
{
    const int b = blockIdx.x;
    const int t = threadIdx.x;
    __shared__ __align__(16) float pooled[256];

    {
        const float4* src = (const float4*)(x + (size_t)b * 65536 + (size_t)t * 256);
        float s = 0.f;
#pragma unroll 8
        for (int i = 0; i < 64; ++i) {
            const float4 v = src[i];
            s += v.x + v.y + v.z + v.w;
        }
        pooled[t] = s * (1.0f / 256.0f);
    }
    __syncthreads();

    if (t < 128) {
        const float4* wr = (const float4*)(embw + (size_t)t * 256);
        float d = 0.f;
#pragma unroll 8
        for (int i = 0; i < 64; ++i) {
            const float4 wv = wr[i];
            const float4 pv = *(const float4*)&pooled[4 * i];
            d = fmaf(wv.x, pv.x, d);
            d = fmaf(wv.y, pv.y, d);
            d = fmaf(wv.z, pv.z, d);
            d = fmaf(wv.w, pv.w, d);
        }
        emb[b * 128 + t] = d + embb[t];
    } else if (t < 160) {
        const int k = t - 128;
        float s = 0.f;
#pragma unroll
        for (int o = 0; o < 8; ++o) {
            const float4 qv = *(const float4*)&csws[((size_t)(b * 256 + k * 8 + o)) * 4];
            s += qv.x + qv.y + qv.z + qv.w;
        }
        cat_act[b * 32 + k] = s * (1.0f / 2048.0f);
    }
}

// ---------------------------------------------------------------------------
extern "C" void kernel_launch(void* const* d_in, const int* in_sizes, int n_in,
                              void* d_out, int out_size, void* d_ws, size_t ws_size,
                              hipStream_t stream) {
    const float* v4   = (const float*)d_in[0];
    const float* w1dw = (const float*)d_in[1];
    const float* w1pw = (const float*)d_in[2];
    const float* bn1g = (const float*)d_in[3];
    const float* bn1b = (const float*)d_in[4];
    const float* bn1m = (const float*)d_in[5];
    const float* bn1v = (const float*)d_in[6];
    const float* w2dw = (const float*)d_in[7];
    const float* w2pw = (const float*)d_in[8];
    const float* bn2g = (const float*)d_in[9];
    const float* bn2b = (const float*)d_in[10];
    const float* bn2m = (const float*)d_in[11];
    const float* bn2v = (const float*)d_in[12];
    const float* catw = (const float*)d_in[13];
    const float* embw = (const float*)d_in[14];
    const float* embb = (const float*)d_in[15];

    float* out        = (float*)d_out;
    float* cat_spikes = out;                    // [32][256][256]
    float* cat_act    = out + 2097152;          // [32][32]
    float* emb        = out + 2098176;          // [32][128]
    float* xout       = out + 2102272;          // [32][256][256]

    char* ws = (char*)d_ws;
    u16* wsW1 = (u16*)ws;                       // 64 KB
    u16* wsW2 = (u16*)(ws + 65536);             // 128 KB
    u16* wsWc = (u16*)(ws + 196608);            // 128 KB
    u16* t1b  = (u16*)(ws + 327680);                        // 32 MB
    u16* t2bT = (u16*)(ws + 327680 + 33554432);             // 16 MB [32][1024][256]
    float* csws = (float*)(ws + 327680 + 33554432 + 16777216); // 128 KB

    // Block 1 (+ weight prep in tail blocks)
    dw1_prep<<<4256, 256, 0, stream>>>(v4, w1dw, t1b, w1pw, w2pw, catw,
                                       wsW1, wsW2, wsWc);
    pw1_v2<<<1024, 256, 0, stream>>>(t1b, wsW1, bn1g, bn1b, bn1m, bn1v, t2bT);
    // Block 2: fused dw2 + pw2
    pw2_v3<<<512, 256, 0, stream>>>(t2bT, wsW2, w2dw, bn2g, bn2b, bn2m, bn2v, xout);
    // Category contraction (partial catsums -> ws)
    cat_v2<<<1024, 256, 0, stream>>>(xout, wsWc, cat_spikes, csws);
    // Final: pooled + embedding + cat_act
    final_kernel<<<32, 256, 0, stream>>>(xout, csws, embw, embb, cat_act, emb);
}

// Round 14
// 102.704 us; speedup vs baseline: 1.1306x; 1.1306x over previous
//
#include <hip/hip_runtime.h>

#define BN_EPS 1e-5f

typedef float f32x4 __attribute__((ext_vector_type(4)));
typedef short short8 __attribute__((ext_vector_type(8)));
typedef unsigned short u16;

__device__ __forceinline__ u16 f2bf(float f) {
    unsigned u = __builtin_bit_cast(unsigned, f);
    unsigned r = (u + 0x7FFFu + ((u >> 16) & 1u)) >> 16;   // round-nearest-even
    return (u16)r;
}
__device__ __forceinline__ float b2f(u16 h) {
    return __builtin_bit_cast(float, (unsigned)h << 16);
}

// two-term XOR swizzle (bits 4-6 of the byte offset)
#define SWZ(row) ((((row) & 7) ^ (((row) >> 3) & 7)) << 4)

// ---------------------------------------------------------------------------
// dw1 + prep fused: blocks [0,4096) do depthwise 3x3 (HW=64, fp32->bf16);
// blocks [4096,4256) convert pw/cat weights to bf16.
// ---------------------------------------------------------------------------
__global__ __launch_bounds__(256) void dw1_prep(
    const float* __restrict__ in, const float* __restrict__ wts,
    u16* __restrict__ out,
    const float* __restrict__ w1, const float* __restrict__ w2,
    const float* __restrict__ wc, u16* __restrict__ o1,
    u16* __restrict__ o2, u16* __restrict__ oc)
{
    const int t = threadIdx.x;
    if (blockIdx.x >= 4096) {
        const int idx = (blockIdx.x - 4096) * 256 + t;     // [0, 40960)
        const float* src; u16* dst; int off;
        if (idx < 8192)       { src = w1; dst = o1; off = idx; }
        else if (idx < 24576) { src = w2; dst = o2; off = idx - 8192; }
        else                  { src = wc; dst = oc; off = idx - 24576; }
        const float4 v = *(const float4*)(src + 4 * (size_t)off);
        ushort4 h;
        h.x = f2bf(v.x); h.y = f2bf(v.y); h.z = f2bf(v.z); h.w = f2bf(v.w);
        *(ushort4*)(dst + 4 * (size_t)off) = h;
        return;
    }

    const int HW = 64;
    const int wq  = t & 15;               // lane within row (16 lanes x 4px)
    const int w0  = wq * 4;
    const int rin = t >> 4;
    const int plane = blockIdx.x;
    const int c     = plane & 127;
    float wt[9];
#pragma unroll
    for (int i = 0; i < 9; ++i) wt[i] = wts[c * 9 + i];
    const float* ip = in  + (size_t)plane * (HW * HW);
    u16*         op = out + (size_t)plane * (HW * HW);

#pragma unroll
    for (int it = 0; it < 4; ++it) {
        const int h = it * 16 + rin;
        const float* rp = ip + h * HW + w0;
        const float4 zero4 = make_float4(0.f, 0.f, 0.f, 0.f);
        const float4 vc = *(const float4*)rp;
        const float4 vt = (h > 0)      ? *(const float4*)(rp - HW) : zero4;
        const float4 vb = (h < HW - 1) ? *(const float4*)(rp + HW) : zero4;

        float lc = __shfl_up(vc.w, 1),  rc = __shfl_down(vc.x, 1);
        float lt = __shfl_up(vt.w, 1),  rt = __shfl_down(vt.x, 1);
        float lb = __shfl_up(vb.w, 1),  rb = __shfl_down(vb.x, 1);
        if (wq == 0)  { lc = 0.f; lt = 0.f; lb = 0.f; }
        if (wq == 15) { rc = 0.f; rt = 0.f; rb = 0.f; }

        float o0 = 0.f, o1v = 0.f, o2v = 0.f, o3v = 0.f;
        o0  = fmaf(lt,   wt[0], fmaf(vt.x, wt[1], fmaf(vt.y, wt[2], o0)));
        o1v = fmaf(vt.x, wt[0], fmaf(vt.y, wt[1], fmaf(vt.z, wt[2], o1v)));
        o2v = fmaf(vt.y, wt[0], fmaf(vt.z, wt[1], fmaf(vt.w, wt[2], o2v)));
        o3v = fmaf(vt.z, wt[0], fmaf(vt.w, wt[1], fmaf(rt,   wt[2], o3v)));
        o0  = fmaf(lc,   wt[3], fmaf(vc.x, wt[4], fmaf(vc.y, wt[5], o0)));
        o1v = fmaf(vc.x, wt[3], fmaf(vc.y, wt[4], fmaf(vc.z, wt[5], o1v)));
        o2v = fmaf(vc.y, wt[3], fmaf(vc.z, wt[4], fmaf(vc.w, wt[5], o2v)));
        o3v = fmaf(vc.z, wt[3], fmaf(vc.w, wt[4], fmaf(rc,   wt[5], o3v)));
        o0  = fmaf(lb,   wt[6], fmaf(vb.x, wt[7], fmaf(vb.y, wt[8], o0)));
        o1v = fmaf(vb.x, wt[6], fmaf(vb.y, wt[7], fmaf(vb.z, wt[8], o1v)));
        o2v = fmaf(vb.y, wt[6], fmaf(vb.z, wt[7], fmaf(vb.w, wt[8], o2v)));
        o3v = fmaf(vb.z, wt[6], fmaf(vb.w, wt[7], fmaf(rb,   wt[8], o3v)));

        ushort4 st;
        st.x = f2bf(o0); st.y = f2bf(o1v); st.z = f2bf(o2v); st.w = f2bf(o3v);
        *(ushort4*)(op + h * HW + w0) = st;
    }
}

// ---------------------------------------------------------------------------
// pw1_v2: one block per (b, py) X-tile. 256o x 128px, K=128 resident.
// ---------------------------------------------------------------------------
__global__ __launch_bounds__(256, 2) void pw1_v2(
    const u16* __restrict__ t1b, const u16* __restrict__ wsW1,
    const float* __restrict__ bg, const float* __restrict__ bb,
    const float* __restrict__ bm, const float* __restrict__ bv,
    u16* __restrict__ t2b)
{
    __shared__ __align__(16) char smem[34816];       // B 32K | sArr 1K | tArr 1K
    float* sArr = (float*)(smem + 32768);
    float* tArr = (float*)(smem + 33792);

    const int bid = blockIdx.x;
    const int b   = bid >> 5;
    const int py  = bid & 31;
    const int p0  = py * 128;
    const int t   = threadIdx.x;

    {
        const float s = bg[t] * rsqrtf(bv[t] + BN_EPS);
        sArr[t] = s;
        tArr[t] = bb[t] - bm[t] * s;
    }

    {
        const u16* xb = t1b + ((size_t)b * 128) * 4096 + p0;
        const int pg = t & 15, cg = t >> 4;
        short8 vin[8];
#pragma unroll
        for (int j = 0; j < 8; ++j)
            vin[j] = *(const short8*)(xb + (size_t)(8 * cg + j) * 4096 + 8 * pg);
#pragma unroll
        for (int k = 0; k < 8; ++k) {
            short8 ov;
            ov[0] = vin[0][k]; ov[1] = vin[1][k]; ov[2] = vin[2][k]; ov[3] = vin[3][k];
            ov[4] = vin[4][k]; ov[5] = vin[5][k]; ov[6] = vin[6][k]; ov[7] = vin[7][k];
            const int row = 8 * pg + k;
            *(short8*)(smem + ((row * 256 + cg * 16) ^ SWZ(row))) = ov;
        }
    }
    __syncthreads();

    const int lane = t & 63, wid = t >> 6;
    const int lr = lane & 15, lg = lane >> 4;
    const int wo = wid * 64;

    f32x4 acc[4][8];
#pragma unroll
    for (int m = 0; m < 4; ++m)
#pragma unroll
        for (int n = 0; n < 8; ++n) acc[m][n] = (f32x4){0.f, 0.f, 0.f, 0.f};

    const u16* wbase = wsW1 + (size_t)(wo + lr) * 128 + lg * 8;
#pragma unroll
    for (int ks = 0; ks < 4; ++ks) {
        short8 af[4];
#pragma unroll
        for (int m = 0; m < 4; ++m)
            af[m] = *(const short8*)(wbase + m * 16 * 128 + ks * 32);
#pragma unroll
        for (int n = 0; n < 8; ++n) {
            const int prow = n * 16 + lr;
            const short8 bfv = *(const short8*)(smem +
                ((prow * 256 + ks * 64 + lg * 16) ^ SWZ(prow)));
#pragma unroll
            for (int m = 0; m < 4; ++m)
                acc[m][n] = __builtin_amdgcn_mfma_f32_16x16x32_bf16(af[m], bfv, acc[m][n], 0, 0, 0);
        }
    }

    u16* outb = t2b + ((size_t)(b * 256) * 32 + py) * 32;
#pragma unroll
    for (int m = 0; m < 4; ++m) {
#pragma unroll
        for (int j = 0; j < 4; ++j) {
            const int o = wo + m * 16 + 4 * lg + j;
            const float s = sArr[o], tt = tArr[o];
#pragma unroll
            for (int n = 0; n < 4; ++n) {
                const float a0 = fmaxf(fmaf(acc[m][n][j],     s, tt), 0.f);
                const float a1 = fmaxf(fmaf(acc[m][n + 4][j], s, tt), 0.f);
                const float vm = fmaxf(a0, a1);
                const float hm = fmaxf(vm, __shfl_xor(vm, 1));
                const unsigned p2 = (unsigned)f2bf(hm) |
                                    ((unsigned)f2bf(__shfl_xor(hm, 2)) << 16);
                const unsigned hi = __shfl_xor(p2, 4);
                if ((lr & 7) == 0) {
                    uint2 w2v; w2v.x = p2; w2v.y = hi;
                    *(uint2*)(outb + (size_t)o * 1024 + n * 8 + (lr >> 1)) = w2v;
                }
            }
        }
    }
}

// ---------------------------------------------------------------------------
// Depthwise 3x3, SAME, lane-contiguous, bf16 in / bf16 out (HW=32 use).
// ---------------------------------------------------------------------------
template<int HW, int LOGW, int NPL, int IPP, int CMASK>
__global__ __launch_bounds__(256) void dw_shfl_bf(
    const u16* __restrict__ in, const float* __restrict__ wts,
    u16* __restrict__ out)
{
    const int t   = threadIdx.x;
    const int LPR = HW / 4;
    const int wq  = t & (LPR - 1);
    const int w0  = wq * 4;
    const int rin = t >> (LOGW - 2);

    for (int pl = 0; pl < NPL; ++pl) {
        const int plane = blockIdx.x * NPL + pl;
        const int c     = plane & CMASK;
        float wt[9];
#pragma unroll
        for (int i = 0; i < 9; ++i) wt[i] = wts[c * 9 + i];
        const u16* ip = in  + (size_t)plane * (HW * HW);
        u16*       op = out + (size_t)plane * (HW * HW);

#pragma unroll
        for (int it = 0; it < IPP; ++it) {
            const int h = it * (1024 / HW) + rin;
            const u16* rp = ip + h * HW + w0;
            float4 vc, vt, vb;
            {
                const ushort4 hcv = *(const ushort4*)rp;
                vc = make_float4(b2f(hcv.x), b2f(hcv.y), b2f(hcv.z), b2f(hcv.w));
            }
            if (h > 0) {
                const ushort4 htv = *(const ushort4*)(rp - HW);
                vt = make_float4(b2f(htv.x), b2f(htv.y), b2f(htv.z), b2f(htv.w));
            } else vt = make_float4(0.f, 0.f, 0.f, 0.f);
            if (h < HW - 1) {
                const ushort4 hbv = *(const ushort4*)(rp + HW);
                vb = make_float4(b2f(hbv.x), b2f(hbv.y), b2f(hbv.z), b2f(hbv.w));
            } else vb = make_float4(0.f, 0.f, 0.f, 0.f);

            float lc = __shfl_up(vc.w, 1),  rc = __shfl_down(vc.x, 1);
            float lt = __shfl_up(vt.w, 1),  rt = __shfl_down(vt.x, 1);
            float lb = __shfl_up(vb.w, 1),  rb = __shfl_down(vb.x, 1);
            if (wq == 0)       { lc = 0.f; lt = 0.f; lb = 0.f; }
            if (wq == LPR - 1) { rc = 0.f; rt = 0.f; rb = 0.f; }

            float o0 = 0.f, o1 = 0.f, o2 = 0.f, o3 = 0.f;
            o0 = fmaf(lt,   wt[0], fmaf(vt.x, wt[1], fmaf(vt.y, wt[2], o0)));
            o1 = fmaf(vt.x, wt[0], fmaf(vt.y, wt[1], fmaf(vt.z, wt[2], o1)));
            o2 = fmaf(vt.y, wt[0], fmaf(vt.z, wt[1], fmaf(vt.w, wt[2], o2)));
            o3 = fmaf(vt.z, wt[0], fmaf(vt.w, wt[1], fmaf(rt,   wt[2], o3)));
            o0 = fmaf(lc,   wt[3], fmaf(vc.x, wt[4], fmaf(vc.y, wt[5], o0)));
            o1 = fmaf(vc.x, wt[3], fmaf(vc.y, wt[4], fmaf(vc.z, wt[5], o1)));
            o2 = fmaf(vc.y, wt[3], fmaf(vc.z, wt[4], fmaf(vc.w, wt[5], o2)));
            o3 = fmaf(vc.z, wt[3], fmaf(vc.w, wt[4], fmaf(rc,   wt[5], o3)));
            o0 = fmaf(lb,   wt[6], fmaf(vb.x, wt[7], fmaf(vb.y, wt[8], o0)));
            o1 = fmaf(vb.x, wt[6], fmaf(vb.y, wt[7], fmaf(vb.z, wt[8], o1)));
            o2 = fmaf(vb.y, wt[6], fmaf(vb.z, wt[7], fmaf(vb.w, wt[8], o2)));
            o3 = fmaf(vb.z, wt[6], fmaf(vb.w, wt[7], fmaf(rb,   wt[8], o3)));

            ushort4 st;
            st.x = f2bf(o0); st.y = f2bf(o1); st.z = f2bf(o2); st.w = f2bf(o3);
            *(ushort4*)(op + h * HW + w0) = st;
        }
    }
}

// ---------------------------------------------------------------------------
// pw2 via bf16 MFMA: 64o x 128px, K=256 as 2 stages.
// ---------------------------------------------------------------------------
__global__ __launch_bounds__(256) void pw2_mfma(
    const u16* __restrict__ t3b, const u16* __restrict__ wsW2,
    const float* __restrict__ bg, const float* __restrict__ bb,
    const float* __restrict__ bm, const float* __restrict__ bv,
    float* __restrict__ xout)
{
    __shared__ __align__(16) char smem[49664];
    float* sArr = (float*)(smem + 49152);
    float* tArr = (float*)(smem + 49408);
    float* Df   = (float*)smem;

    const int bid = blockIdx.x;
    const int o0  = ((bid >> 3) & 3) * 64;
    const int pxb = (bid >> 5) * 8 + (bid & 7);   // [0,256)
    const int px  = pxb & 7;
    const int b   = pxb >> 3;
    const int p0  = px * 128;
    const int t   = threadIdx.x;

    const int lane = t & 63, wid = t >> 6;
    const int lr = lane & 15, lg = lane >> 4;
    const int wo = (wid >> 1) * 32;
    const int wp = (wid & 1) * 64;

    f32x4 acc[2][4];
#pragma unroll
    for (int m = 0; m < 2; ++m)
#pragma unroll
        for (int n = 0; n < 4; ++n) acc[m][n] = (f32x4){0.f, 0.f, 0.f, 0.f};

#pragma unroll
    for (int ko = 0; ko < 2; ++ko) {
        if (ko) __syncthreads();

#pragma unroll
        for (int i = 0; i < 4; ++i) {
            const int li = i * 256 + t;
            const int ol = li >> 4;
            const int f8 = li & 15;
            const short8 wv = *(const short8*)(wsW2 + (size_t)(o0 + ol) * 256 + ko * 128 + 8 * f8);
            *(short8*)(smem + ((ol * 256 + f8 * 16) ^ SWZ(ol))) = wv;
        }

        {
            const u16* xb = t3b + ((size_t)b * 256 + ko * 128) * 1024 + p0;
            const int pg = t & 15, cg = t >> 4;
            short8 vin[8];
#pragma unroll
            for (int j = 0; j < 8; ++j)
                vin[j] = *(const short8*)(xb + (size_t)(8 * cg + j) * 1024 + 8 * pg);
#pragma unroll
            for (int k = 0; k < 8; ++k) {
                short8 ov;
                ov[0] = vin[0][k]; ov[1] = vin[1][k]; ov[2] = vin[2][k]; ov[3] = vin[3][k];
                ov[4] = vin[4][k]; ov[5] = vin[5][k]; ov[6] = vin[6][k]; ov[7] = vin[7][k];
                const int row = 8 * pg + k;
                *(short8*)(smem + 16384 + ((row * 256 + cg * 16) ^ SWZ(row))) = ov;
            }
        }

        if (ko == 0 && t < 64) {
            const int o = o0 + t;
            const float s = bg[o] * rsqrtf(bv[o] + BN_EPS);
            sArr[t] = s;
            tArr[t] = bb[o] - bm[o] * s;
        }
        __syncthreads();

#pragma unroll
        for (int ks = 0; ks < 4; ++ks) {
            short8 af[2];
#pragma unroll
            for (int m = 0; m < 2; ++m) {
                const int rowm = wo + m * 16 + lr;
                af[m] = *(const short8*)(smem + ((rowm * 256 + ks * 64 + lg * 16) ^ SWZ(rowm)));
            }
#pragma unroll
            for (int n = 0; n < 4; ++n) {
                const int prow = wp + n * 16 + lr;
                const short8 bfv = *(const short8*)(smem + 16384 +
                    ((prow * 256 + ks * 64 + lg * 16) ^ SWZ(prow)));
                acc[0][n] = __builtin_amdgcn_mfma_f32_16x16x32_bf16(af[0], bfv, acc[0][n], 0, 0, 0);
                acc[1][n] = __builtin_amdgcn_mfma_f32_16x16x32_bf16(af[1], bfv, acc[1][n], 0, 0, 0);
            }
        }
    }
    __syncthreads();

    float sv[2][4], tv[2][4];
#pragma unroll
    for (int m = 0; m < 2; ++m)
#pragma unroll
        for (int j = 0; j < 4; ++j) {
            const int ol = wo + m * 16 + 4 * lg + j;
            sv[m][j] = sArr[ol];
            tv[m][j] = tArr[ol];
        }
#pragma unroll
    for (int m = 0; m < 2; ++m)
#pragma unroll
        for (int n = 0; n < 4; ++n)
#pragma unroll
            for (int j = 0; j < 4; ++j) {
                const int ol = wo + m * 16 + 4 * lg + j;
                const int pl = wp + n * 16 + lr;
                const float val = fmaf(acc[m][n][j], sv[m][j], tv[m][j]);
                Df[ol * 130 + pl] = fmaxf(val, 0.f);
            }
    __syncthreads();

#pragma unroll
    for (int i = 0; i < 8; ++i) {
        const int oi = i * 256 + t;
        const int o  = oi >> 5;
        const int q  = oi & 31;
        const int prl = q >> 4;
        const int pc  = q & 15;
        const float a0 = Df[o * 130 + prl * 64 + 2 * pc];
        const float a1 = Df[o * 130 + prl * 64 + 2 * pc + 1];
        const float b0 = Df[o * 130 + prl * 64 + 32 + 2 * pc];
        const float b1 = Df[o * 130 + prl * 64 + 32 + 2 * pc + 1];
        xout[(((size_t)(b * 256 + o0 + o)) * 16 + 2 * px + prl) * 16 + pc] =
            fmaxf(fmaxf(a0, a1), fmaxf(b0, b1));
    }
}

// ---------------------------------------------------------------------------
// cat_v2: 1024 blocks = (b, m-block, px-quarter). Single-stage.
// ---------------------------------------------------------------------------
__global__ __launch_bounds__(256) void cat_v2(
    const float* __restrict__ x, const u16* __restrict__ wsWc,
    float* __restrict__ spikes, float* __restrict__ csws)
{
    __shared__ __align__(16) char smem[49664];   // A 16K @0 | B 32K @16384 | cs
    float* cs = (float*)(smem + 49152);          // [4][32]

    const int bid = blockIdx.x;
    const int g   = (bid >> 6) * 8 + (bid & 7);  // [0,128)
    const int m0  = ((bid >> 3) & 7) * 32;
    const int b   = g >> 2;
    const int q   = g & 3;
    const int px0 = q * 64;
    const int t   = threadIdx.x;

#pragma unroll
    for (int i = 0; i < 4; ++i) {
        const int li = i * 256 + t;
        const int ml = li >> 5, ch = li & 31;
        const short8 wv = *(const short8*)(wsWc + (size_t)(m0 + ml) * 256 + ch * 8);
        *(short8*)(smem + ((ml * 512 + ch * 16) ^ SWZ(ml))) = wv;
    }

    const float* xb = x + (size_t)b * 65536;
#pragma unroll
    for (int i = 0; i < 4; ++i) {
        const int li = i * 256 + t;
        const int pq = li & 15;
        const int cg = li >> 4;
        const float4 v0 = *(const float4*)(xb + (size_t)(4 * cg + 0) * 256 + px0 + 4 * pq);
        const float4 v1 = *(const float4*)(xb + (size_t)(4 * cg + 1) * 256 + px0 + 4 * pq);
        const float4 v2 = *(const float4*)(xb + (size_t)(4 * cg + 2) * 256 + px0 + 4 * pq);
        const float4 v3 = *(const float4*)(xb + (size_t)(4 * cg + 3) * 256 + px0 + 4 * pq);
        ushort4 h0, h1, h2, h3;
        h0.x = f2bf(v0.x); h0.y = f2bf(v1.x); h0.z = f2bf(v2.x); h0.w = f2bf(v3.x);
        h1.x = f2bf(v0.y); h1.y = f2bf(v1.y); h1.z = f2bf(v2.y); h1.w = f2bf(v3.y);
        h2.x = f2bf(v0.z); h2.y = f2bf(v1.z); h2.z = f2bf(v2.z); h2.w = f2bf(v3.z);
        h3.x = f2bf(v0.w); h3.y = f2bf(v1.w); h3.z = f2bf(v2.w); h3.w = f2bf(v3.w);
        const int p_ = 4 * pq;
        *(ushort4*)(smem + 16384 + (((p_ + 0) * 512 + cg * 8) ^ SWZ(p_ + 0))) = h0;
        *(ushort4*)(smem + 16384 + (((p_ + 1) * 512 + cg * 8) ^ SWZ(p_ + 1))) = h1;
        *(ushort4*)(smem + 16384 + (((p_ + 2) * 512 + cg * 8) ^ SWZ(p_ + 2))) = h2;
        *(ushort4*)(smem + 16384 + (((p_ + 3) * 512 + cg * 8) ^ SWZ(p_ + 3))) = h3;
    }
    __syncthreads();

    const int lane = t & 63, wid = t >> 6;
    const int lr = lane & 15, lg = lane >> 4;

    f32x4 acc[2];
    acc[0] = (f32x4){0.f, 0.f, 0.f, 0.f};
    acc[1] = (f32x4){0.f, 0.f, 0.f, 0.f};

#pragma unroll
    for (int ks = 0; ks < 8; ++ks) {
        const int prow = wid * 16 + lr;
        const short8 b8 = *(const short8*)(smem + 16384 +
            ((prow * 512 + ks * 64 + lg * 16) ^ SWZ(prow)));
#pragma unroll
        for (int mi = 0; mi < 2; ++mi) {
            const int rowm = mi * 16 + lr;
            const short8 a8 = *(const short8*)(smem +
                ((rowm * 512 + ks * 64 + lg * 16) ^ SWZ(rowm)));
            acc[mi] = __builtin_amdgcn_mfma_f32_16x16x32_bf16(a8, b8, acc[mi], 0, 0, 0);
        }
    }

#pragma unroll
    for (int mi = 0; mi < 2; ++mi) {
#pragma unroll
        for (int j = 0; j < 4; ++j) {
            const int m  = m0 + mi * 16 + 4 * lg + j;
            const int px = px0 + wid * 16 + lr;
            spikes[((size_t)(b * 256 + m)) * 256 + px] = acc[mi][j];
            float s = acc[mi][j];
            s += __shfl_xor(s, 1, 64);
            s += __shfl_xor(s, 2, 64);
            s += __shfl_xor(s, 4, 64);
            s += __shfl_xor(s, 8, 64);
            if (lr == 0) cs[wid * 32 + mi * 16 + 4 * lg + j] = s;
        }
    }
    __syncthreads();
    if (t < 32) {
        const float p = cs[t] + cs[32 + t] + cs[64 + t] + cs[96 + t];
        csws[((size_t)(b * 256 + m0 + t)) * 4 + q] = p;
    }
}

// ---------------------------------------------------------------------------
// final: pooled mean + embedding GEMV + cat_act from partials.
// ---------------------------------------------------------------------------
__global__ __launch_bounds__(256) void final_kernel(
    const float* __restrict__ x, const float* __restrict__ csws,
    const float* __restrict__ embw, const float* __restrict__ embb,
    float* __restrict__ cat_act, float* __restrict__ emb)
{
    const int b = blockIdx.x;
    const int t = threadIdx.x;
    __shared__ __align__(16) float pooled[256];

    {
        const float4* src = (const float4*)(x + (size_t)b * 65536 + (size_t)t * 256);
        float s = 0.f;
#pragma unroll 8
        for (int i = 0; i < 64; ++i) {
            const float4 v = src[i];
            s += v.x + v.y + v.z + v.w;
        }
        pooled[t] = s * (1.0f / 256.0f);
    }
    __syncthreads();

    if (t < 128) {
        const float4* wr = (const float4*)(embw + (size_t)t * 256);
        float d = 0.f;
#pragma unroll 8
        for (int i = 0; i < 64; ++i) {
            const float4 wv = wr[i];
            const float4 pv = *(const float4*)&pooled[4 * i];
            d = fmaf(wv.x, pv.x, d);
            d = fmaf(wv.y, pv.y, d);
            d = fmaf(wv.z, pv.z, d);
            d = fmaf(wv.w, pv.w, d);
        }
        emb[b * 128 + t] = d + embb[t];
    } else if (t < 160) {
        const int k = t - 128;
        float s = 0.f;
#pragma unroll
        for (int o = 0; o < 8; ++o) {
            const float4 qv = *(const float4*)&csws[((size_t)(b * 256 + k * 8 + o)) * 4];
            s += qv.x + qv.y + qv.z + qv.w;
        }
        cat_act[b * 32 + k] = s * (1.0f / 2048.0f);
    }
}

// ---------------------------------------------------------------------------
extern "C" void kernel_launch(void* const* d_in, const int* in_sizes, int n_in,
                              void* d_out, int out_size, void* d_ws, size_t ws_size,
                              hipStream_t stream) {
    const float* v4   = (const float*)d_in[0];
    const float* w1dw = (const float*)d_in[1];
    const float* w1pw = (const float*)d_in[2];
    const float* bn1g = (const float*)d_in[3];
    const float* bn1b = (const float*)d_in[4];
    const float* bn1m = (const float*)d_in[5];
    const float* bn1v = (const float*)d_in[6];
    const float* w2dw = (const float*)d_in[7];
    const float* w2pw = (const float*)d_in[8];
    const float* bn2g = (const float*)d_in[9];
    const float* bn2b = (const float*)d_in[10];
    const float* bn2m = (const float*)d_in[11];
    const float* bn2v = (const float*)d_in[12];
    const float* catw = (const float*)d_in[13];
    const float* embw = (const float*)d_in[14];
    const float* embb = (const float*)d_in[15];

    float* out        = (float*)d_out;
    float* cat_spikes = out;                    // [32][256][256]
    float* cat_act    = out + 2097152;          // [32][32]
    float* emb        = out + 2098176;          // [32][128]
    float* xout       = out + 2102272;          // [32][256][256]

    char* ws = (char*)d_ws;
    u16* wsW1 = (u16*)ws;                       // 64 KB
    u16* wsW2 = (u16*)(ws + 65536);             // 128 KB
    u16* wsWc = (u16*)(ws + 196608);            // 128 KB
    u16* t1b  = (u16*)(ws + 327680);                        // 32 MB
    u16* t2b  = (u16*)(ws + 327680 + 33554432);             // 16 MB
    u16* t3b  = (u16*)(ws + 327680 + 33554432 + 16777216);  // 16 MB
    float* csws = (float*)(ws + 327680 + 33554432 + 16777216 + 16777216); // 128 KB

    // Block 1 (+ weight prep in tail blocks)
    dw1_prep<<<4256, 256, 0, stream>>>(v4, w1dw, t1b, w1pw, w2pw, catw,
                                       wsW1, wsW2, wsWc);
    pw1_v2<<<1024, 256, 0, stream>>>(t1b, wsW1, bn1g, bn1b, bn1m, bn1v, t2b);
    // Block 2
    dw_shfl_bf<32, 5, 4, 1, 255><<<2048, 256, 0, stream>>>(t2b, w2dw, t3b);
    pw2_mfma<<<1024, 256, 0, stream>>>(t3b, wsW2, bn2g, bn2b, bn2m, bn2v, xout);
    // Category contraction (partial catsums -> ws)
    cat_v2<<<1024, 256, 0, stream>>>(xout, wsWc, cat_spikes, csws);
    // Final: pooled + embedding + cat_act
    final_kernel<<<32, 256, 0, stream>>>(xout, csws, embw, embb, cat_act, emb);
}